// Round 2
// baseline (32752.707 us; speedup 1.0000x reference)
//
#include <hip/hip_runtime.h>
#include <hip/hip_fp16.h>
#include <math.h>

// Persistent RK45 (Dormand-Prince, FSAL) integrator for
//   dy/dt = y * (r + A@y + eps@P[d(t)]),  n=4096, up to 512 adaptive steps.
// R9: 128 blocks x 512 threads, half-block emulation of R7's 256x256 layout.
//   Threads [0,256) emulate old block 2b, threads [256,512) old block 2b+1:
//   identical per-thread A fragments, fma chains, wave-reduce order, kval sum
//   order and err-partial order -> k's and accept decisions are BITWISE
//   identical to R7/R8 (absmax must stay exactly 0.0078125).
// Why: R8 post-mortem -- per-stage 4.3us = compute 0.6 + bulk 0.8 + sync ~3.
//   R8's tagged all-poll congested the coherence point (1M loads/sweep, 8MB,
//   >=2 sweeps/stage); R7 had 3-4 serialized hops (flag->block0->bword).
//   R9 sync: publish+waitcnt ACK -> ONE flag/block -> flat detect (wave0's 64
//   lanes poll one flag-PAIR each = 64 coalesced 8B loads/sweep/block, 64KB
//   device-wide -- 100x less than R8) -> one 16KB bulk pull. 2 round-trips,
//   no aggregator hop, no congestion, 128-way tail instead of 256.
// A stays permanently in registers as fp16 (zero steady-state HBM traffic).

#define N        4096
#define NBLK     128
#define NTHR     512
#define ROWS     32          // rows per block = two old 16-row half-blocks
#define HROWS    16
#define MAXSTEP  512
#define PERTS    8

typedef unsigned long long ull;

static_assert(NBLK * ROWS == N, "row partition");
static_assert(NTHR == 2 * 256, "two half-blocks");

__device__ __forceinline__ float4 ld4(const float* p){ return *reinterpret_cast<const float4*>(p); }
__device__ __forceinline__ void   st4(float* p, float4 v){ *reinterpret_cast<float4*>(p) = v; }

__global__ void __launch_bounds__(NTHR, 2)
mbpert_rk45_kernel(const float* __restrict__ x, const int* __restrict__ tptr,
                   const float* __restrict__ r, const float* __restrict__ A,
                   const float* __restrict__ eps, const float* __restrict__ Pm,
                   float* __restrict__ out, float* __restrict__ W, int Tm)
{
  __shared__ float khist[6][N];        // 96 KB k-history (gfx950: 160KB LDS/WG)
  __shared__ float part_sm[2 * HROWS * 4];  // [half][row][wave-in-half]
  __shared__ float ys_rows[ROWS];      // stage vector at our 32 row indices
  __shared__ float ysb_rows[ROWS];     // base vector at our 32 row indices
  __shared__ float r_sh[ROWS];
  __shared__ float eps_sh[ROWS * PERTS];
  __shared__ float P_sh[32 * PERTS];
  __shared__ float epr_sh[ROWS];
  __shared__ float es_sh;

  const int tid  = threadIdx.x;
  const int b    = blockIdx.x;
  const int t    = tid & 255;          // old-thread id within half-block
  const int hb   = tid >> 8;           // half index (0: old block 2b, 1: 2b+1)
  const int lane = tid & 63;
  const int wv   = tid >> 6;           // wave 0..7
  const int wh   = wv & 3;             // wave within half
  const int rowbase = b * ROWS;
  const int rb_h    = rowbase + hb * HROWS;   // this half's global row base
  const bool rowthr = (t < HROWS);            // tid in [0,16) or [256,272)
  const int rowidx  = hb * HROWS + (t & 15);  // row-in-block, valid if rowthr

  unsigned* flags = reinterpret_cast<unsigned*>(W);   // [NBLK] per-block gens
  float*    errF  = W + 128;                          // [256] old-order err partials
  ull*      kx0   = reinterpret_cast<ull*>(W + 512);  // [N/2] exchange buf A
  ull*      kx1   = kx0 + (N / 2);                    // [N/2] exchange buf B

  // ---- persistent LDS constants ----
  if (tid < ROWS)             r_sh[tid]   = r[rowbase + tid];
  if (tid < ROWS * PERTS)     eps_sh[tid] = eps[rowbase * PERTS + tid];
  if (tid < (Tm + 1) * PERTS) P_sh[tid]   = Pm[tid];
  if (tid < ROWS)             ysb_rows[tid] = x[rowbase + tid];

  // ---- A fragment -> registers (fp16), once; identical to old layout ----
  // Half-thread t owns cols (q*256+t)*4..+3 (q=0..3) of its half's 16 rows.
  __half2 Af[HROWS][8];
  #pragma unroll
  for (int rr = 0; rr < HROWS; rr++){
    const float* Ar = A + (size_t)(rb_h + rr) * N;
    #pragma unroll
    for (int q = 0; q < 4; q++){
      int c = (q * 256 + t) * 4;
      float4 a = ld4(Ar + c);
      Af[rr][2*q]   = __floats2half2_rn(a.x, a.y);
      Af[rr][2*q+1] = __floats2half2_rn(a.z, a.w);
    }
  }

  float4 ysbf[4], ysf[4];              // base / stage vector fragments (fp32)
  #pragma unroll
  for (int q = 0; q < 4; q++) ysbf[q] = ld4(x + (q * 256 + t) * 4);
  __syncthreads();

  const float t_end = (float)(*tptr);
  const float Tf    = (float)Tm;
  float tc = 0.0f;
  float hs = t_end * 0.01f;
  unsigned gen = 0;

  // matvec from registers: same fma/reduce order as R7 -> bitwise-identical
  auto mv = [&](){
    float acc[HROWS];
    #pragma unroll
    for (int rr = 0; rr < HROWS; rr++) acc[rr] = 0.0f;
    #pragma unroll
    for (int q = 0; q < 4; q++){
      float4 y = ysf[q];
      #pragma unroll
      for (int rr = 0; rr < HROWS; rr++){
        float2 lo = __half22float2(Af[rr][2*q]);
        float2 hi = __half22float2(Af[rr][2*q+1]);
        acc[rr] = fmaf(lo.x, y.x, fmaf(lo.y, y.y, fmaf(hi.x, y.z, fmaf(hi.y, y.w, acc[rr]))));
      }
    }
    __syncthreads();                   // part_sm free from previous stage
    #pragma unroll
    for (int rr = 0; rr < HROWS; rr++){
      float s = acc[rr];
      #pragma unroll
      for (int off = 32; off; off >>= 1) s += __shfl_xor(s, off, 64);
      if (lane == 0) part_sm[hb * 64 + rr * 4 + wh] = s;
    }
    __syncthreads();
  };

  // k for row `rowidx` (rowthr): y_s * (r + A@y_s + eps@P[d])
  auto kval = [&](float ts) -> float {
    int d = (int)((Tf * ts) / 30.0f);
    d = d < 0 ? 0 : (d > Tm ? Tm : d);
    const float* pp = &part_sm[hb * 64 + (t & 15) * 4];
    float dot = pp[0] + pp[1] + pp[2] + pp[3];
    float ep = 0.f;
    #pragma unroll
    for (int p = 0; p < PERTS; p++) ep += eps_sh[rowidx * PERTS + p] * P_sh[d * PERTS + p];
    return ys_rows[rowidx] * (r_sh[rowidx] + dot + ep);
  };

  // ys = ysb + hs * sum(cf[m] * khist[sli[m]]) over this half-thread's 16 cols
  auto build = [&](const int* sli, const float* cf, int nk){
    #pragma unroll
    for (int q = 0; q < 4; q++){
      int c = (q * 256 + t) * 4;
      float4 v = ysbf[q];
      for (int m = 0; m < nk; m++){
        float cc = hs * cf[m];
        float4 kv = ld4(&khist[sli[m]][c]);
        v.x = fmaf(cc, kv.x, v.x); v.y = fmaf(cc, kv.y, v.y);
        v.z = fmaf(cc, kv.z, v.z); v.w = fmaf(cc, kv.w, v.w);
      }
      ysf[q] = v;
      int o = c - rb_h;                // both halves redundantly build; disjoint row writes
      if (o >= 0 && o < HROWS) st4(&ys_rows[hb * HROWS + o], v);
    }
    __syncthreads();
  };

  // publish 32 k's (+2 err partials), waitcnt ACK, flag, flat detect, bulk pull
  auto exchange = [&](int slot, float kv, bool werr, float ev0, float ev1){
    ++gen;
    ull* kx = (gen & 1u) ? kx1 : kx0;            // double buffer by parity
    if (wv == 0 || wv == 4){
      float klo = __shfl(kv, (lane << 1),     64);
      float khi = __shfl(kv, (lane << 1) | 1, 64);
      if (lane < 8){
        union { float2 f; ull u; } cv;
        cv.f = make_float2(klo, khi);
        __hip_atomic_store(&kx[(rowbase >> 1) + hb * 8 + lane], cv.u,
                           __ATOMIC_RELAXED, __HIP_MEMORY_SCOPE_AGENT);
      }
      if (werr && tid == 0){
        __hip_atomic_store(&errF[2*b],   ev0, __ATOMIC_RELAXED, __HIP_MEMORY_SCOPE_AGENT);
        __hip_atomic_store(&errF[2*b+1], ev1, __ATOMIC_RELAXED, __HIP_MEMORY_SCOPE_AGENT);
      }
      __builtin_amdgcn_sched_barrier(0);
      __builtin_amdgcn_s_waitcnt(0);             // k/err stores at coherence point
      __builtin_amdgcn_sched_barrier(0);
    }
    __syncthreads();                             // all publishes ACKed
    if (tid == 0)
      __hip_atomic_store(&flags[b], gen, __ATOMIC_RELAXED, __HIP_MEMORY_SCOPE_AGENT);
    if (wv == 0){
      // flat detect: 64 lanes x one flag-pair = 64 coalesced 8B loads/sweep
      const ull* fl2 = reinterpret_cast<const ull*>(flags);
      for (;;){
        ull v = __hip_atomic_load(&fl2[lane], __ATOMIC_RELAXED, __HIP_MEMORY_SCOPE_AGENT);
        bool ok = ((unsigned)v >= gen) && ((unsigned)(v >> 32) >= gen);
        if (__all(ok)) break;
        __builtin_amdgcn_s_sleep(2);
      }
    }
    __syncthreads();
    // ---- bulk pull: 2048 ull, 4 per thread, coalesced ----
    float2* kh2 = reinterpret_cast<float2*>(&khist[slot][0]);
    #pragma unroll
    for (int w = 0; w < 4; w++){
      union { float2 f; ull u; } cv;
      cv.u = __hip_atomic_load(&kx[w * NTHR + tid], __ATOMIC_RELAXED, __HIP_MEMORY_SCOPE_AGENT);
      kh2[w * NTHR + tid] = cv.f;
    }
    if (werr && wv == 0){
      // same order as R7 (errF[lane + j*64], j asc, xor tree) -> bitwise match
      float es = 0.f;
      #pragma unroll
      for (int j = 0; j < 4; j++)
        es += __hip_atomic_load(&errF[lane + j * 64],
                                __ATOMIC_RELAXED, __HIP_MEMORY_SCOPE_AGENT);
      #pragma unroll
      for (int off = 32; off; off >>= 1) es += __shfl_xor(es, off, 64);
      if (lane == 0) es_sh = es;
    }
    __syncthreads();                             // khist[slot]/es_sh ready
  };

  int sl[6] = {0, 1, 2, 3, 4, 5};      // logical k1..k6 -> physical LDS slots
  bool exhausted = true;

  for (int n = 0; n < MAXSTEP; ++n){
    if (n > 0){
      float es = es_sh;                          // set by last stage-7 exchange
      float enorm = sqrtf(es * (1.0f / (float)N));
      bool accept = (enorm <= 1.0f);
      if (accept){
        tc += hs;
        int tmp = sl[0]; sl[0] = sl[1]; sl[1] = tmp;  // FSAL: k1 <- k7
        #pragma unroll
        for (int q = 0; q < 4; q++) ysbf[q] = ysf[q];
        if (tid < ROWS) ysb_rows[tid] = ys_rows[tid];
      }
      float fac = 0.9f * powf(enorm + 1e-10f, -0.2f);
      fac = fminf(fmaxf(fac, 0.2f), 10.0f);
      hs *= fac;
      __syncthreads();
    }
    if (tc >= t_end) { exhausted = false; break; }
    hs = fminf(hs, t_end - tc);
    if (!(hs > 0.0f)) { exhausted = false; break; }

    if (n == 0){
      // ---- stage 1 (once ever; FSAL covers later steps) ----
      #pragma unroll
      for (int q = 0; q < 4; q++){
        ysf[q] = ysbf[q];
        int c = (q * 256 + t) * 4, o = c - rb_h;
        if (o >= 0 && o < HROWS) st4(&ys_rows[hb * HROWS + o], ysf[q]);
      }
      __syncthreads();
      mv();
      float kv = rowthr ? kval(tc) : 0.f;
      exchange(sl[0], kv, false, 0.f, 0.f);
    }

    // ---- stage 2 ----
    { const float cf[1] = {0.2f}; const int s_[1] = {sl[0]};
      build(s_, cf, 1); mv();
      float kv = rowthr ? kval(tc + 0.2f * hs) : 0.f;
      exchange(sl[1], kv, false, 0.f, 0.f); }

    // ---- stage 3 ----
    { const float cf[2] = {3.f/40.f, 9.f/40.f}; const int s_[2] = {sl[0], sl[1]};
      build(s_, cf, 2); mv();
      float kv = rowthr ? kval(tc + 0.3f * hs) : 0.f;
      exchange(sl[2], kv, false, 0.f, 0.f); }

    // ---- stage 4 ----
    { const float cf[3] = {44.f/45.f, -56.f/15.f, 32.f/9.f};
      const int s_[3] = {sl[0], sl[1], sl[2]};
      build(s_, cf, 3); mv();
      float kv = rowthr ? kval(tc + 0.8f * hs) : 0.f;
      exchange(sl[3], kv, false, 0.f, 0.f); }

    // ---- stage 5 ----
    { const float cf[4] = {19372.f/6561.f, -25360.f/2187.f, 64448.f/6561.f, -212.f/729.f};
      const int s_[4] = {sl[0], sl[1], sl[2], sl[3]};
      build(s_, cf, 4); mv();
      float kv = rowthr ? kval(tc + (8.f/9.f) * hs) : 0.f;
      exchange(sl[4], kv, false, 0.f, 0.f); }

    // ---- stage 6 ----
    { const float cf[5] = {9017.f/3168.f, -355.f/33.f, 46732.f/5247.f, 49.f/176.f, -5103.f/18656.f};
      const int s_[5] = {sl[0], sl[1], sl[2], sl[3], sl[4]};
      build(s_, cf, 5); mv();
      float kv = rowthr ? kval(tc + hs) : 0.f;
      exchange(sl[5], kv, false, 0.f, 0.f); }

    // ---- stage 7: ys = y5 candidate; err partials; k7 -> sl[1] (k2 dead) ----
    { const float cf[5] = {35.f/384.f, 500.f/1113.f, 125.f/192.f, -2187.f/6784.f, 11.f/84.f};
      const int s_[5] = {sl[0], sl[2], sl[3], sl[4], sl[5]};
      build(s_, cf, 5);                // ys == y5 candidate; ys_rows updated
      mv();
      float k7v = 0.f, ev0 = 0.f, ev1 = 0.f;
      if (rowthr){
        k7v = kval(tc + hs);
        int gi = rowbase + rowidx;
        float e = (71.f/57600.f)  * khist[sl[0]][gi] - (71.f/16695.f)    * khist[sl[2]][gi]
                + (71.f/1920.f)   * khist[sl[3]][gi] - (17253.f/339200.f)* khist[sl[4]][gi]
                + (22.f/525.f)    * khist[sl[5]][gi] - (1.f/40.f)        * k7v;
        e *= hs;
        float sc = 1e-6f + 1e-3f * fmaxf(fabsf(ysb_rows[rowidx]), fabsf(ys_rows[rowidx]));
        float q = e / sc;
        epr_sh[rowidx] = q * q;
      }
      __syncthreads();
      if (tid == 0){
        float s0 = 0.f, s1 = 0.f;                // old blocks 2b / 2b+1 order
        #pragma unroll
        for (int i = 0; i < HROWS; i++) s0 += epr_sh[i];
        #pragma unroll
        for (int i = 0; i < HROWS; i++) s1 += epr_sh[HROWS + i];
        ev0 = s0; ev1 = s1;
      }
      exchange(sl[1], k7v, true, ev0, ev1);      // k7 + 2 err partials
    }
  }

  if (exhausted){
    // apply the final (iteration 511) accept decision, as the reference does
    float es = es_sh;
    bool accept = sqrtf(es * (1.0f / (float)N)) <= 1.0f;
    if (tid < ROWS) out[rowbase + tid] = accept ? ys_rows[tid] : ysb_rows[tid];
  } else {
    if (tid < ROWS) out[rowbase + tid] = ysb_rows[tid];
  }
}

extern "C" void kernel_launch(void* const* d_in, const int* in_sizes, int n_in,
                              void* d_out, int out_size, void* d_ws, size_t ws_size,
                              hipStream_t stream)
{
  const float* x   = (const float*)d_in[0];
  const int*   tp  = (const int*)  d_in[1];
  const float* r   = (const float*)d_in[2];
  const float* A   = (const float*)d_in[3];
  const float* eps = (const float*)d_in[4];
  const float* Pm  = (const float*)d_in[5];
  float* out = (float*)d_out;
  float* W   = (float*)d_ws;
  int Tm = in_sizes[5] / PERTS - 1;   // P rows - 1  (== 30)

  // zero flags + errF (first 2KB); ws re-poisoned per call
  hipMemsetAsync(d_ws, 0, 2048, stream);
  mbpert_rk45_kernel<<<dim3(NBLK), dim3(NTHR), 0, stream>>>(
      x, tp, r, A, eps, Pm, out, W, Tm);
}

// Round 3
// 32079.279 us; speedup vs baseline: 1.0210x; 1.0210x over previous
//
#include <hip/hip_runtime.h>
#include <hip/hip_fp16.h>
#include <math.h>

// Persistent RK45 (Dormand-Prince, FSAL) integrator for
//   dy/dt = y * (r + A@y + eps@P[d(t)]),  n=4096, up to 512 adaptive steps.
// R10 = R9 with the launch-bounds bug fixed.
//   R9 post-mortem: __launch_bounds__(512,2) capped VGPR at 128; the A
//   fragment alone needs 128 VGPRs -> compiler spilled Af to scratch ->
//   FETCH 934MB (scratch reload every mv), dur 32.7ms. absmax stayed
//   0.0078125, so the half-block emulation itself is bitwise-correct.
//   (512,1) allows 2 waves/SIMD @ <=256 VGPR -> ~212 VGPR like R7, no spill.
// Structure (unchanged from R9): 128 blocks x 512 threads; threads [0,256)
//   emulate old block 2b, [256,512) old block 2b+1 -> identical fma chains,
//   reduce order, err order -> trajectory bitwise-identical to R7.
// Sync: publish 32 k's + waitcnt ACK -> ONE flag/block -> flat detect
//   (wave0's 64 lanes poll one flag-PAIR each = 64 coalesced 8B loads/sweep)
//   -> one 16KB bulk pull. No aggregator hops (R7), no all-poll congestion
//   (R8), 128-way straggler tail instead of 256.
// A stays permanently in registers as fp16 (zero steady-state HBM traffic).

#define N        4096
#define NBLK     128
#define NTHR     512
#define ROWS     32          // rows per block = two old 16-row half-blocks
#define HROWS    16
#define MAXSTEP  512
#define PERTS    8

typedef unsigned long long ull;

static_assert(NBLK * ROWS == N, "row partition");
static_assert(NTHR == 2 * 256, "two half-blocks");

__device__ __forceinline__ float4 ld4(const float* p){ return *reinterpret_cast<const float4*>(p); }
__device__ __forceinline__ void   st4(float* p, float4 v){ *reinterpret_cast<float4*>(p) = v; }

__global__ void __launch_bounds__(NTHR, 1)
mbpert_rk45_kernel(const float* __restrict__ x, const int* __restrict__ tptr,
                   const float* __restrict__ r, const float* __restrict__ A,
                   const float* __restrict__ eps, const float* __restrict__ Pm,
                   float* __restrict__ out, float* __restrict__ W, int Tm)
{
  __shared__ float khist[6][N];        // 96 KB k-history (gfx950: 160KB LDS/WG)
  __shared__ float part_sm[2 * HROWS * 4];  // [half][row][wave-in-half]
  __shared__ float ys_rows[ROWS];      // stage vector at our 32 row indices
  __shared__ float ysb_rows[ROWS];     // base vector at our 32 row indices
  __shared__ float r_sh[ROWS];
  __shared__ float eps_sh[ROWS * PERTS];
  __shared__ float P_sh[32 * PERTS];
  __shared__ float epr_sh[ROWS];
  __shared__ float es_sh;

  const int tid  = threadIdx.x;
  const int b    = blockIdx.x;
  const int t    = tid & 255;          // old-thread id within half-block
  const int hb   = tid >> 8;           // half index (0: old block 2b, 1: 2b+1)
  const int lane = tid & 63;
  const int wv   = tid >> 6;           // wave 0..7
  const int wh   = wv & 3;             // wave within half
  const int rowbase = b * ROWS;
  const int rb_h    = rowbase + hb * HROWS;   // this half's global row base
  const bool rowthr = (t < HROWS);            // tid in [0,16) or [256,272)
  const int rowidx  = hb * HROWS + (t & 15);  // row-in-block, valid if rowthr

  unsigned* flags = reinterpret_cast<unsigned*>(W);   // [NBLK] per-block gens
  float*    errF  = W + 128;                          // [256] old-order err partials
  ull*      kx0   = reinterpret_cast<ull*>(W + 512);  // [N/2] exchange buf A
  ull*      kx1   = kx0 + (N / 2);                    // [N/2] exchange buf B

  // ---- persistent LDS constants ----
  if (tid < ROWS)             r_sh[tid]   = r[rowbase + tid];
  if (tid < ROWS * PERTS)     eps_sh[tid] = eps[rowbase * PERTS + tid];
  if (tid < (Tm + 1) * PERTS) P_sh[tid]   = Pm[tid];
  if (tid < ROWS)             ysb_rows[tid] = x[rowbase + tid];

  // ---- A fragment -> registers (fp16), once; identical to old layout ----
  // Half-thread t owns cols (q*256+t)*4..+3 (q=0..3) of its half's 16 rows.
  __half2 Af[HROWS][8];
  #pragma unroll
  for (int rr = 0; rr < HROWS; rr++){
    const float* Ar = A + (size_t)(rb_h + rr) * N;
    #pragma unroll
    for (int q = 0; q < 4; q++){
      int c = (q * 256 + t) * 4;
      float4 a = ld4(Ar + c);
      Af[rr][2*q]   = __floats2half2_rn(a.x, a.y);
      Af[rr][2*q+1] = __floats2half2_rn(a.z, a.w);
    }
  }

  float4 ysbf[4], ysf[4];              // base / stage vector fragments (fp32)
  #pragma unroll
  for (int q = 0; q < 4; q++) ysbf[q] = ld4(x + (q * 256 + t) * 4);
  __syncthreads();

  const float t_end = (float)(*tptr);
  const float Tf    = (float)Tm;
  float tc = 0.0f;
  float hs = t_end * 0.01f;
  unsigned gen = 0;

  // matvec from registers: same fma/reduce order as R7 -> bitwise-identical
  auto mv = [&](){
    float acc[HROWS];
    #pragma unroll
    for (int rr = 0; rr < HROWS; rr++) acc[rr] = 0.0f;
    #pragma unroll
    for (int q = 0; q < 4; q++){
      float4 y = ysf[q];
      #pragma unroll
      for (int rr = 0; rr < HROWS; rr++){
        float2 lo = __half22float2(Af[rr][2*q]);
        float2 hi = __half22float2(Af[rr][2*q+1]);
        acc[rr] = fmaf(lo.x, y.x, fmaf(lo.y, y.y, fmaf(hi.x, y.z, fmaf(hi.y, y.w, acc[rr]))));
      }
    }
    __syncthreads();                   // part_sm free from previous stage
    #pragma unroll
    for (int rr = 0; rr < HROWS; rr++){
      float s = acc[rr];
      #pragma unroll
      for (int off = 32; off; off >>= 1) s += __shfl_xor(s, off, 64);
      if (lane == 0) part_sm[hb * 64 + rr * 4 + wh] = s;
    }
    __syncthreads();
  };

  // k for row `rowidx` (rowthr): y_s * (r + A@y_s + eps@P[d])
  auto kval = [&](float ts) -> float {
    int d = (int)((Tf * ts) / 30.0f);
    d = d < 0 ? 0 : (d > Tm ? Tm : d);
    const float* pp = &part_sm[hb * 64 + (t & 15) * 4];
    float dot = pp[0] + pp[1] + pp[2] + pp[3];
    float ep = 0.f;
    #pragma unroll
    for (int p = 0; p < PERTS; p++) ep += eps_sh[rowidx * PERTS + p] * P_sh[d * PERTS + p];
    return ys_rows[rowidx] * (r_sh[rowidx] + dot + ep);
  };

  // ys = ysb + hs * sum(cf[m] * khist[sli[m]]) over this half-thread's 16 cols
  auto build = [&](const int* sli, const float* cf, int nk){
    #pragma unroll
    for (int q = 0; q < 4; q++){
      int c = (q * 256 + t) * 4;
      float4 v = ysbf[q];
      for (int m = 0; m < nk; m++){
        float cc = hs * cf[m];
        float4 kv = ld4(&khist[sli[m]][c]);
        v.x = fmaf(cc, kv.x, v.x); v.y = fmaf(cc, kv.y, v.y);
        v.z = fmaf(cc, kv.z, v.z); v.w = fmaf(cc, kv.w, v.w);
      }
      ysf[q] = v;
      int o = c - rb_h;                // both halves redundantly build; disjoint row writes
      if (o >= 0 && o < HROWS) st4(&ys_rows[hb * HROWS + o], v);
    }
    __syncthreads();
  };

  // publish 32 k's (+2 err partials), waitcnt ACK, flag, flat detect, bulk pull
  auto exchange = [&](int slot, float kv, bool werr, float ev0, float ev1){
    ++gen;
    ull* kx = (gen & 1u) ? kx1 : kx0;            // double buffer by parity
    if (wv == 0 || wv == 4){
      float klo = __shfl(kv, (lane << 1),     64);
      float khi = __shfl(kv, (lane << 1) | 1, 64);
      if (lane < 8){
        union { float2 f; ull u; } cv;
        cv.f = make_float2(klo, khi);
        __hip_atomic_store(&kx[(rowbase >> 1) + hb * 8 + lane], cv.u,
                           __ATOMIC_RELAXED, __HIP_MEMORY_SCOPE_AGENT);
      }
      if (werr && tid == 0){
        __hip_atomic_store(&errF[2*b],   ev0, __ATOMIC_RELAXED, __HIP_MEMORY_SCOPE_AGENT);
        __hip_atomic_store(&errF[2*b+1], ev1, __ATOMIC_RELAXED, __HIP_MEMORY_SCOPE_AGENT);
      }
      __builtin_amdgcn_sched_barrier(0);
      __builtin_amdgcn_s_waitcnt(0);             // k/err stores at coherence point
      __builtin_amdgcn_sched_barrier(0);
    }
    __syncthreads();                             // all publishes ACKed
    if (tid == 0)
      __hip_atomic_store(&flags[b], gen, __ATOMIC_RELAXED, __HIP_MEMORY_SCOPE_AGENT);
    if (wv == 0){
      // flat detect: 64 lanes x one flag-pair = 64 coalesced 8B loads/sweep
      const ull* fl2 = reinterpret_cast<const ull*>(flags);
      for (;;){
        ull v = __hip_atomic_load(&fl2[lane], __ATOMIC_RELAXED, __HIP_MEMORY_SCOPE_AGENT);
        bool ok = ((unsigned)v >= gen) && ((unsigned)(v >> 32) >= gen);
        if (__all(ok)) break;
        __builtin_amdgcn_s_sleep(2);
      }
    }
    __syncthreads();
    // ---- bulk pull: 2048 ull, 4 per thread, coalesced ----
    float2* kh2 = reinterpret_cast<float2*>(&khist[slot][0]);
    #pragma unroll
    for (int w = 0; w < 4; w++){
      union { float2 f; ull u; } cv;
      cv.u = __hip_atomic_load(&kx[w * NTHR + tid], __ATOMIC_RELAXED, __HIP_MEMORY_SCOPE_AGENT);
      kh2[w * NTHR + tid] = cv.f;
    }
    if (werr && wv == 0){
      // same order as R7 (errF[lane + j*64], j asc, xor tree) -> bitwise match
      float es = 0.f;
      #pragma unroll
      for (int j = 0; j < 4; j++)
        es += __hip_atomic_load(&errF[lane + j * 64],
                                __ATOMIC_RELAXED, __HIP_MEMORY_SCOPE_AGENT);
      #pragma unroll
      for (int off = 32; off; off >>= 1) es += __shfl_xor(es, off, 64);
      if (lane == 0) es_sh = es;
    }
    __syncthreads();                             // khist[slot]/es_sh ready
  };

  int sl[6] = {0, 1, 2, 3, 4, 5};      // logical k1..k6 -> physical LDS slots
  bool exhausted = true;

  for (int n = 0; n < MAXSTEP; ++n){
    if (n > 0){
      float es = es_sh;                          // set by last stage-7 exchange
      float enorm = sqrtf(es * (1.0f / (float)N));
      bool accept = (enorm <= 1.0f);
      if (accept){
        tc += hs;
        int tmp = sl[0]; sl[0] = sl[1]; sl[1] = tmp;  // FSAL: k1 <- k7
        #pragma unroll
        for (int q = 0; q < 4; q++) ysbf[q] = ysf[q];
        if (tid < ROWS) ysb_rows[tid] = ys_rows[tid];
      }
      float fac = 0.9f * powf(enorm + 1e-10f, -0.2f);
      fac = fminf(fmaxf(fac, 0.2f), 10.0f);
      hs *= fac;
      __syncthreads();
    }
    if (tc >= t_end) { exhausted = false; break; }
    hs = fminf(hs, t_end - tc);
    if (!(hs > 0.0f)) { exhausted = false; break; }

    if (n == 0){
      // ---- stage 1 (once ever; FSAL covers later steps) ----
      #pragma unroll
      for (int q = 0; q < 4; q++){
        ysf[q] = ysbf[q];
        int c = (q * 256 + t) * 4, o = c - rb_h;
        if (o >= 0 && o < HROWS) st4(&ys_rows[hb * HROWS + o], ysf[q]);
      }
      __syncthreads();
      mv();
      float kv = rowthr ? kval(tc) : 0.f;
      exchange(sl[0], kv, false, 0.f, 0.f);
    }

    // ---- stage 2 ----
    { const float cf[1] = {0.2f}; const int s_[1] = {sl[0]};
      build(s_, cf, 1); mv();
      float kv = rowthr ? kval(tc + 0.2f * hs) : 0.f;
      exchange(sl[1], kv, false, 0.f, 0.f); }

    // ---- stage 3 ----
    { const float cf[2] = {3.f/40.f, 9.f/40.f}; const int s_[2] = {sl[0], sl[1]};
      build(s_, cf, 2); mv();
      float kv = rowthr ? kval(tc + 0.3f * hs) : 0.f;
      exchange(sl[2], kv, false, 0.f, 0.f); }

    // ---- stage 4 ----
    { const float cf[3] = {44.f/45.f, -56.f/15.f, 32.f/9.f};
      const int s_[3] = {sl[0], sl[1], sl[2]};
      build(s_, cf, 3); mv();
      float kv = rowthr ? kval(tc + 0.8f * hs) : 0.f;
      exchange(sl[3], kv, false, 0.f, 0.f); }

    // ---- stage 5 ----
    { const float cf[4] = {19372.f/6561.f, -25360.f/2187.f, 64448.f/6561.f, -212.f/729.f};
      const int s_[4] = {sl[0], sl[1], sl[2], sl[3]};
      build(s_, cf, 4); mv();
      float kv = rowthr ? kval(tc + (8.f/9.f) * hs) : 0.f;
      exchange(sl[4], kv, false, 0.f, 0.f); }

    // ---- stage 6 ----
    { const float cf[5] = {9017.f/3168.f, -355.f/33.f, 46732.f/5247.f, 49.f/176.f, -5103.f/18656.f};
      const int s_[5] = {sl[0], sl[1], sl[2], sl[3], sl[4]};
      build(s_, cf, 5); mv();
      float kv = rowthr ? kval(tc + hs) : 0.f;
      exchange(sl[5], kv, false, 0.f, 0.f); }

    // ---- stage 7: ys = y5 candidate; err partials; k7 -> sl[1] (k2 dead) ----
    { const float cf[5] = {35.f/384.f, 500.f/1113.f, 125.f/192.f, -2187.f/6784.f, 11.f/84.f};
      const int s_[5] = {sl[0], sl[2], sl[3], sl[4], sl[5]};
      build(s_, cf, 5);                // ys == y5 candidate; ys_rows updated
      mv();
      float k7v = 0.f, ev0 = 0.f, ev1 = 0.f;
      if (rowthr){
        k7v = kval(tc + hs);
        int gi = rowbase + rowidx;
        float e = (71.f/57600.f)  * khist[sl[0]][gi] - (71.f/16695.f)    * khist[sl[2]][gi]
                + (71.f/1920.f)   * khist[sl[3]][gi] - (17253.f/339200.f)* khist[sl[4]][gi]
                + (22.f/525.f)    * khist[sl[5]][gi] - (1.f/40.f)        * k7v;
        e *= hs;
        float sc = 1e-6f + 1e-3f * fmaxf(fabsf(ysb_rows[rowidx]), fabsf(ys_rows[rowidx]));
        float q = e / sc;
        epr_sh[rowidx] = q * q;
      }
      __syncthreads();
      if (tid == 0){
        float s0 = 0.f, s1 = 0.f;                // old blocks 2b / 2b+1 order
        #pragma unroll
        for (int i = 0; i < HROWS; i++) s0 += epr_sh[i];
        #pragma unroll
        for (int i = 0; i < HROWS; i++) s1 += epr_sh[HROWS + i];
        ev0 = s0; ev1 = s1;
      }
      exchange(sl[1], k7v, true, ev0, ev1);      // k7 + 2 err partials
    }
  }

  if (exhausted){
    // apply the final (iteration 511) accept decision, as the reference does
    float es = es_sh;
    bool accept = sqrtf(es * (1.0f / (float)N)) <= 1.0f;
    if (tid < ROWS) out[rowbase + tid] = accept ? ys_rows[tid] : ysb_rows[tid];
  } else {
    if (tid < ROWS) out[rowbase + tid] = ysb_rows[tid];
  }
}

extern "C" void kernel_launch(void* const* d_in, const int* in_sizes, int n_in,
                              void* d_out, int out_size, void* d_ws, size_t ws_size,
                              hipStream_t stream)
{
  const float* x   = (const float*)d_in[0];
  const int*   tp  = (const int*)  d_in[1];
  const float* r   = (const float*)d_in[2];
  const float* A   = (const float*)d_in[3];
  const float* eps = (const float*)d_in[4];
  const float* Pm  = (const float*)d_in[5];
  float* out = (float*)d_out;
  float* W   = (float*)d_ws;
  int Tm = in_sizes[5] / PERTS - 1;   // P rows - 1  (== 30)

  // zero flags + errF (first 2KB); ws re-poisoned per call
  hipMemsetAsync(d_ws, 0, 2048, stream);
  mbpert_rk45_kernel<<<dim3(NBLK), dim3(NTHR), 0, stream>>>(
      x, tp, r, A, eps, Pm, out, W, Tm);
}

// Round 4
// 21363.469 us; speedup vs baseline: 1.5331x; 1.5016x over previous
//
#include <hip/hip_runtime.h>
#include <hip/hip_fp16.h>
#include <math.h>

// Persistent RK45 (Dormand-Prince, FSAL) integrator for
//   dy/dt = y * (r + A@y + eps@P[d(t)]),  n=4096, up to 512 adaptive steps.
// R11 = R7 (256 blocks x 256 threads, centralized two-phase barrier) with
// ONE change: the bulk k-pull is now L2-CACHED.
//   R9/R10 post-mortem: 512-thread workgroups get a hard 128-VGPR budget on
//   this toolchain (both (512,2) and (512,1)) -> Af spills -> 33ms. 256-thr
//   blocks get 212 VGPR (R7 proven). Consolidation via 512-thr blocks is dead.
//   R11 theory: R7's 4.34us/stage = compute 0.55 + publish/ACK 0.35 + agg
//   hops ~0.8 + bulk pull ~1.5-2. The pull used agent-scope relaxed atomic
//   loads, which bypass the non-coherent per-XCD L2 -> 256 blocks x 16KB =
//   4MB/stage all served by the coherence point. Now: after detection, issue
//   __builtin_amdgcn_fence(ACQUIRE, "agent") (emits L1+L2 invalidate per the
//   gfx94x/gfx950 memory model), then pull with PLAIN float4 loads -> first
//   block per XCD fills L2, the other ~31 hit it. ~32x less coherence-point
//   traffic. Parity double-buffer + two-phase separation makes cached reads
//   stale-safe (the fence kills the only stale copy: our own L2's).
// A stays permanently in registers as fp16 (zero steady-state HBM traffic).

#define N        4096
#define NBLK     256
#define NTHR     256
#define ROWS     16          // rows of A per block (NBLK*ROWS == N)
#define MAXSTEP  512
#define PERTS    8

typedef unsigned long long ull;

static_assert(NBLK * ROWS == N, "row partition");
static_assert(NTHR * 16 == N, "column partition (4 float4 per thread)");

__device__ __forceinline__ float4 ld4(const float* p){ return *reinterpret_cast<const float4*>(p); }
__device__ __forceinline__ void   st4(float* p, float4 v){ *reinterpret_cast<float4*>(p) = v; }

__global__ void __launch_bounds__(NTHR, 1)
mbpert_rk45_kernel(const float* __restrict__ x, const int* __restrict__ tptr,
                   const float* __restrict__ r, const float* __restrict__ A,
                   const float* __restrict__ eps, const float* __restrict__ Pm,
                   float* __restrict__ out, float* __restrict__ W, int Tm)
{
  __shared__ float khist[6][N];        // 96 KB k-history (gfx950: 160KB LDS/WG)
  __shared__ float part_sm[ROWS * 4];  // per-wave matvec partials
  __shared__ float ys_rows[ROWS];      // stage vector at our 16 row indices
  __shared__ float ysb_rows[ROWS];     // base vector at our 16 row indices
  __shared__ float r_sh[ROWS];
  __shared__ float eps_sh[ROWS * PERTS];
  __shared__ float P_sh[32 * PERTS];
  __shared__ float epr_sh[ROWS];
  __shared__ float es_sh;

  const int tid = threadIdx.x;
  const int b   = blockIdx.x;
  const int rowbase = b * ROWS;
  const int lane = tid & 63;
  const int wv   = tid >> 6;

  unsigned* flags    = reinterpret_cast<unsigned*>(W);       // [256] per-block stage flags
  float*    err_part = W + 256;                              // [256] err partials
  ull*      bword    = reinterpret_cast<ull*>(W + 512);      // packed (gen<<32 | err bits)
  ull*      kx0u     = reinterpret_cast<ull*>(W + 1024);     // [N/2] exchange buf A
  ull*      kx1u     = reinterpret_cast<ull*>(W + 1024 + N); // [N/2] exchange buf B

  // ---- persistent LDS constants ----
  if (tid < ROWS)             r_sh[tid]   = r[rowbase + tid];
  if (tid < ROWS * PERTS)     eps_sh[tid] = eps[rowbase * PERTS + tid];
  if (tid < (Tm + 1) * PERTS) P_sh[tid]   = Pm[tid];
  if (tid < ROWS)             ysb_rows[tid] = x[rowbase + tid];

  // ---- A fragment -> registers (fp16), once ----
  // Thread owns cols (q*256+tid)*4..+3 (q=0..3) of rows rowbase..rowbase+15.
  __half2 Af[ROWS][8];
  #pragma unroll
  for (int rr = 0; rr < ROWS; rr++){
    const float* Ar = A + (size_t)(rowbase + rr) * N;
    #pragma unroll
    for (int q = 0; q < 4; q++){
      int c = (q * NTHR + tid) * 4;
      float4 a = ld4(Ar + c);
      Af[rr][2*q]   = __floats2half2_rn(a.x, a.y);
      Af[rr][2*q+1] = __floats2half2_rn(a.z, a.w);
    }
  }

  float4 ysbf[4], ysf[4];              // base / stage vector fragments (fp32)
  #pragma unroll
  for (int q = 0; q < 4; q++) ysbf[q] = ld4(x + (q * NTHR + tid) * 4);
  __syncthreads();

  const float t_end = (float)(*tptr);
  const float Tf    = (float)Tm;
  float t = 0.0f;
  float h = t_end * 0.01f;
  unsigned gen = 0;

  // matvec from registers: acc over our 16 cols, wave-reduce, park in part_sm
  auto mv = [&](){
    float acc[ROWS];
    #pragma unroll
    for (int rr = 0; rr < ROWS; rr++) acc[rr] = 0.0f;
    #pragma unroll
    for (int q = 0; q < 4; q++){
      float4 y = ysf[q];
      #pragma unroll
      for (int rr = 0; rr < ROWS; rr++){
        float2 lo = __half22float2(Af[rr][2*q]);
        float2 hi = __half22float2(Af[rr][2*q+1]);
        acc[rr] = fmaf(lo.x, y.x, fmaf(lo.y, y.y, fmaf(hi.x, y.z, fmaf(hi.y, y.w, acc[rr]))));
      }
    }
    __syncthreads();                   // part_sm free from previous stage
    #pragma unroll
    for (int rr = 0; rr < ROWS; rr++){
      float s = acc[rr];
      #pragma unroll
      for (int off = 32; off; off >>= 1) s += __shfl_xor(s, off, 64);
      if (lane == 0) part_sm[rr * 4 + wv] = s;
    }
    __syncthreads();
  };

  // k for row `tid` (tid<ROWS): y_s * (r + A@y_s + eps@P[d])
  auto kval = [&](float ts) -> float {
    int d = (int)((Tf * ts) / 30.0f);
    d = d < 0 ? 0 : (d > Tm ? Tm : d);
    float dot = part_sm[tid*4] + part_sm[tid*4+1] + part_sm[tid*4+2] + part_sm[tid*4+3];
    float ep = 0.f;
    #pragma unroll
    for (int p = 0; p < PERTS; p++) ep += eps_sh[tid * PERTS + p] * P_sh[d * PERTS + p];
    return ys_rows[tid] * (r_sh[tid] + dot + ep);
  };

  // ys = ysb + h * sum(cf[m] * khist[sli[m]]) over our 16 columns
  auto build = [&](const int* sli, const float* cf, int nk){
    #pragma unroll
    for (int q = 0; q < 4; q++){
      int c = (q * NTHR + tid) * 4;
      float4 v = ysbf[q];
      for (int m = 0; m < nk; m++){
        float cc = h * cf[m];
        float4 kv = ld4(&khist[sli[m]][c]);
        v.x = fmaf(cc, kv.x, v.x); v.y = fmaf(cc, kv.y, v.y);
        v.z = fmaf(cc, kv.z, v.z); v.w = fmaf(cc, kv.w, v.w);
      }
      ysf[q] = v;
      int o = c - rowbase;             // c,rowbase multiples of 4/16: full containment
      if (o >= 0 && o < ROWS) st4(&ys_rows[o], v);
    }
    __syncthreads();
  };

  // publish own 16 k's (+err), two-phase barrier via block 0, pull 4096 into khist[slot]
  auto exchange = [&](int slot, float kv, bool werr, float errv){
    ++gen;
    ull* kx = (gen & 1u) ? kx1u : kx0u;          // double buffer by parity
    if (wv == 0){
      float kvn = __shfl_down(kv, 1, 64);
      if ((lane & 1) == 0 && lane < ROWS){
        union { float2 f; ull u; } cv;
        cv.f = make_float2(kv, kvn);
        __hip_atomic_store(&kx[(rowbase >> 1) + (lane >> 1)], cv.u,
                           __ATOMIC_RELAXED, __HIP_MEMORY_SCOPE_AGENT);
      }
      if (werr && lane == 0)
        __hip_atomic_store(&err_part[b], errv, __ATOMIC_RELAXED, __HIP_MEMORY_SCOPE_AGENT);
    }
    __syncthreads();                             // all stage work done
    if (tid == 0){
      __builtin_amdgcn_sched_barrier(0);
      __builtin_amdgcn_s_waitcnt(0);             // kx/err stores at coherence point
      __builtin_amdgcn_sched_barrier(0);
      __hip_atomic_store(&flags[b], gen, __ATOMIC_RELAXED, __HIP_MEMORY_SCOPE_AGENT);
    }
    if (b == 0){
      // ---- aggregator: scan all 256 flags, then broadcast one packed word ----
      if (wv == 0){
        for (;;){
          bool ok = true;
          #pragma unroll
          for (int j = 0; j < 4; j++){
            unsigned f = __hip_atomic_load(&flags[j * 64 + lane],
                                           __ATOMIC_RELAXED, __HIP_MEMORY_SCOPE_AGENT);
            ok = ok && (f >= gen);
          }
          if (__all(ok)) break;
          __builtin_amdgcn_s_sleep(2);
        }
        float es = 0.f;
        if (werr){                               // same order as R5 read_err -> bitwise identical
          #pragma unroll
          for (int j = 0; j < 4; j++)
            es += __hip_atomic_load(&err_part[lane + j * 64],
                                    __ATOMIC_RELAXED, __HIP_MEMORY_SCOPE_AGENT);
          #pragma unroll
          for (int off = 32; off; off >>= 1) es += __shfl_xor(es, off, 64);
        }
        if (lane == 0){
          if (werr) es_sh = es;
          ull pk = ((ull)gen << 32) | (ull)__float_as_uint(es);
          __builtin_amdgcn_sched_barrier(0);
          __builtin_amdgcn_s_waitcnt(0);
          __builtin_amdgcn_sched_barrier(0);
          __hip_atomic_store(bword, pk, __ATOMIC_RELAXED, __HIP_MEMORY_SCOPE_AGENT);
        }
      }
      __syncthreads();
    } else {
      // ---- follower: poll the single broadcast word ----
      if (tid == 0){
        for (;;){
          ull w = __hip_atomic_load(bword, __ATOMIC_RELAXED, __HIP_MEMORY_SCOPE_AGENT);
          if ((unsigned)(w >> 32) >= gen){
            if (werr) es_sh = __uint_as_float((unsigned)(w & 0xffffffffu));
            break;
          }
          __builtin_amdgcn_s_sleep(2);
        }
      }
      __syncthreads();
    }
    // ---- all blocks: acquire fence (invalidate L1 + per-XCD L2), then pull
    //      the full k-vector with PLAIN cacheable float4 loads: first block
    //      on an XCD fills L2 from the coherence point, the rest hit L2. ----
    __builtin_amdgcn_fence(__ATOMIC_ACQUIRE, "agent");
    const float4* kx4 = reinterpret_cast<const float4*>(kx);
    float4*       kh4 = reinterpret_cast<float4*>(&khist[slot][0]);
    #pragma unroll
    for (int i = 0; i < 4; i++)                  // 4 x 16B/thread, coalesced
      kh4[i * NTHR + tid] = kx4[i * NTHR + tid];
    __syncthreads();
  };

  int sl[6] = {0, 1, 2, 3, 4, 5};      // logical k1..k6 -> physical LDS slots
  bool exhausted = true;

  for (int n = 0; n < MAXSTEP; ++n){
    if (n > 0){
      float es = es_sh;                          // set by last stage-7 exchange
      float enorm = sqrtf(es * (1.0f / (float)N));
      bool accept = (enorm <= 1.0f);
      if (accept){
        t += h;
        int tmp = sl[0]; sl[0] = sl[1]; sl[1] = tmp;  // FSAL: k1 <- k7 (in k2's slot)
        #pragma unroll
        for (int q = 0; q < 4; q++) ysbf[q] = ysf[q];
        if (tid < ROWS) ysb_rows[tid] = ys_rows[tid];
      }
      float fac = 0.9f * powf(enorm + 1e-10f, -0.2f);
      fac = fminf(fmaxf(fac, 0.2f), 10.0f);
      h *= fac;
      __syncthreads();
    }
    if (t >= t_end) { exhausted = false; break; }
    h = fminf(h, t_end - t);
    if (!(h > 0.0f)) { exhausted = false; break; }

    if (n == 0){
      // ---- stage 1 (once ever; FSAL covers later steps) ----
      #pragma unroll
      for (int q = 0; q < 4; q++){
        ysf[q] = ysbf[q];
        int c = (q * NTHR + tid) * 4, o = c - rowbase;
        if (o >= 0 && o < ROWS) st4(&ys_rows[o], ysf[q]);
      }
      __syncthreads();
      mv();
      float kv = (tid < ROWS) ? kval(t) : 0.f;
      exchange(sl[0], kv, false, 0.f);
    }

    // ---- stage 2 ----
    { const float cf[1] = {0.2f}; const int s_[1] = {sl[0]};
      build(s_, cf, 1); mv();
      float kv = (tid < ROWS) ? kval(t + 0.2f * h) : 0.f;
      exchange(sl[1], kv, false, 0.f); }

    // ---- stage 3 ----
    { const float cf[2] = {3.f/40.f, 9.f/40.f}; const int s_[2] = {sl[0], sl[1]};
      build(s_, cf, 2); mv();
      float kv = (tid < ROWS) ? kval(t + 0.3f * h) : 0.f;
      exchange(sl[2], kv, false, 0.f); }

    // ---- stage 4 ----
    { const float cf[3] = {44.f/45.f, -56.f/15.f, 32.f/9.f};
      const int s_[3] = {sl[0], sl[1], sl[2]};
      build(s_, cf, 3); mv();
      float kv = (tid < ROWS) ? kval(t + 0.8f * h) : 0.f;
      exchange(sl[3], kv, false, 0.f); }

    // ---- stage 5 ----
    { const float cf[4] = {19372.f/6561.f, -25360.f/2187.f, 64448.f/6561.f, -212.f/729.f};
      const int s_[4] = {sl[0], sl[1], sl[2], sl[3]};
      build(s_, cf, 4); mv();
      float kv = (tid < ROWS) ? kval(t + (8.f/9.f) * h) : 0.f;
      exchange(sl[4], kv, false, 0.f); }

    // ---- stage 6 ----
    { const float cf[5] = {9017.f/3168.f, -355.f/33.f, 46732.f/5247.f, 49.f/176.f, -5103.f/18656.f};
      const int s_[5] = {sl[0], sl[1], sl[2], sl[3], sl[4]};
      build(s_, cf, 5); mv();
      float kv = (tid < ROWS) ? kval(t + h) : 0.f;
      exchange(sl[5], kv, false, 0.f); }

    // ---- stage 7: ys = y5 candidate; err partial; k7 -> sl[1] (k2 dead) ----
    { const float cf[5] = {35.f/384.f, 500.f/1113.f, 125.f/192.f, -2187.f/6784.f, 11.f/84.f};
      const int s_[5] = {sl[0], sl[2], sl[3], sl[4], sl[5]};
      build(s_, cf, 5);                // ys == y5 candidate; ys_rows updated
      mv();
      float k7v = 0.f, errv = 0.f;
      if (tid < ROWS){
        k7v = kval(t + h);
        int gi = rowbase + tid;
        float e = (71.f/57600.f)  * khist[sl[0]][gi] - (71.f/16695.f)    * khist[sl[2]][gi]
                + (71.f/1920.f)   * khist[sl[3]][gi] - (17253.f/339200.f)* khist[sl[4]][gi]
                + (22.f/525.f)    * khist[sl[5]][gi] - (1.f/40.f)        * k7v;
        e *= h;
        float sc = 1e-6f + 1e-3f * fmaxf(fabsf(ysb_rows[tid]), fabsf(ys_rows[tid]));
        float q = e / sc;
        epr_sh[tid] = q * q;
      }
      __syncthreads();
      if (tid == 0){
        float s = 0.f;
        #pragma unroll
        for (int i = 0; i < ROWS; i++) s += epr_sh[i];
        errv = s;
      }
      exchange(sl[1], k7v, true, errv);          // barrier + err broadcast + k7 fetch
    }
  }

  if (exhausted){
    // apply the final (iteration 511) accept decision, as the reference does
    float es = es_sh;
    bool accept = sqrtf(es * (1.0f / (float)N)) <= 1.0f;
    if (tid < ROWS) out[rowbase + tid] = accept ? ys_rows[tid] : ysb_rows[tid];
  } else {
    if (tid < ROWS) out[rowbase + tid] = ysb_rows[tid];
  }
}

extern "C" void kernel_launch(void* const* d_in, const int* in_sizes, int n_in,
                              void* d_out, int out_size, void* d_ws, size_t ws_size,
                              hipStream_t stream)
{
  const float* x   = (const float*)d_in[0];
  const int*   tp  = (const int*)  d_in[1];
  const float* r   = (const float*)d_in[2];
  const float* A   = (const float*)d_in[3];
  const float* eps = (const float*)d_in[4];
  const float* Pm  = (const float*)d_in[5];
  float* out = (float*)d_out;
  float* W   = (float*)d_ws;
  int Tm = in_sizes[5] / PERTS - 1;   // P rows - 1  (== 30)

  // zero flags / err partials / broadcast word (ws re-poisoned per call)
  hipMemsetAsync(d_ws, 0, 4096, stream);
  mbpert_rk45_kernel<<<dim3(NBLK), dim3(NTHR), 0, stream>>>(
      x, tp, r, A, eps, Pm, out, W, Tm);
}

// Round 5
// 13977.141 us; speedup vs baseline: 2.3433x; 1.5285x over previous
//
#include <hip/hip_runtime.h>
#include <hip/hip_fp16.h>
#include <math.h>

// Persistent RK45 (Dormand-Prince, FSAL) integrator for
//   dy/dt = y * (r + A@y + eps@P[d(t)]),  n=4096, up to 512 adaptive steps.
// R12 = R7 with two independent sync-path changes (numerics untouched):
//  1) FLAT DETECT: drop block-0 aggregator + bword broadcast (2 serialized
//     store-ACK/poll hops, ~0.8-1.0us/stage). Every block's wave0 scans all
//     256 flags itself: 64 lanes x 2 coalesced 8B atomic loads = 1 round
//     trip/sweep, 16K loads/sweep device-wide (60x less than R8's congested
//     all-poll), s_sleep backoff. Same condition block 0 evaluated; stage-7
//     es reduced per-block in R7's exact order -> bitwise-identical
//     trajectory.
//  2) WIDE UNCACHED PULL: 4x global_load_dwordx4 sc0 sc1 (same coherence
//     bits as agent-scope atomic loads, 2x wider than ull) -> half the pull
//     issue/queueing at the coherence point.
// R11 post-mortem: L2-cached pull + per-stage acquire-fence = +8ms (fence
// invalidates serialize; blocks mutually destroy fills). Caching the
// exchange payload is structurally dead; bypass loads are the right path.
// R9/R10: 512-thr workgroups hard-cap VGPR at 128 -> Af spills; 256-thr only.
// A stays permanently in registers as fp16 (zero steady-state HBM traffic).

#define N        4096
#define NBLK     256
#define NTHR     256
#define ROWS     16          // rows of A per block (NBLK*ROWS == N)
#define MAXSTEP  512
#define PERTS    8

typedef unsigned long long ull;

static_assert(NBLK * ROWS == N, "row partition");
static_assert(NTHR * 16 == N, "column partition (4 float4 per thread)");

__device__ __forceinline__ float4 ld4(const float* p){ return *reinterpret_cast<const float4*>(p); }
__device__ __forceinline__ void   st4(float* p, float4 v){ *reinterpret_cast<float4*>(p) = v; }

__global__ void __launch_bounds__(NTHR, 1)
mbpert_rk45_kernel(const float* __restrict__ x, const int* __restrict__ tptr,
                   const float* __restrict__ r, const float* __restrict__ A,
                   const float* __restrict__ eps, const float* __restrict__ Pm,
                   float* __restrict__ out, float* __restrict__ W, int Tm)
{
  __shared__ float khist[6][N];        // 96 KB k-history (gfx950: 160KB LDS/WG)
  __shared__ float part_sm[ROWS * 4];  // per-wave matvec partials
  __shared__ float ys_rows[ROWS];      // stage vector at our 16 row indices
  __shared__ float ysb_rows[ROWS];     // base vector at our 16 row indices
  __shared__ float r_sh[ROWS];
  __shared__ float eps_sh[ROWS * PERTS];
  __shared__ float P_sh[32 * PERTS];
  __shared__ float epr_sh[ROWS];
  __shared__ float es_sh;

  const int tid = threadIdx.x;
  const int b   = blockIdx.x;
  const int rowbase = b * ROWS;
  const int lane = tid & 63;
  const int wv   = tid >> 6;

  unsigned* flags    = reinterpret_cast<unsigned*>(W);       // [256] per-block stage flags
  float*    err_part = W + 256;                              // [256] err partials
  ull*      kx0u     = reinterpret_cast<ull*>(W + 1024);     // [N/2] exchange buf A
  ull*      kx1u     = reinterpret_cast<ull*>(W + 1024 + N); // [N/2] exchange buf B

  // ---- persistent LDS constants ----
  if (tid < ROWS)             r_sh[tid]   = r[rowbase + tid];
  if (tid < ROWS * PERTS)     eps_sh[tid] = eps[rowbase * PERTS + tid];
  if (tid < (Tm + 1) * PERTS) P_sh[tid]   = Pm[tid];
  if (tid < ROWS)             ysb_rows[tid] = x[rowbase + tid];

  // ---- A fragment -> registers (fp16), once ----
  // Thread owns cols (q*256+tid)*4..+3 (q=0..3) of rows rowbase..rowbase+15.
  __half2 Af[ROWS][8];
  #pragma unroll
  for (int rr = 0; rr < ROWS; rr++){
    const float* Ar = A + (size_t)(rowbase + rr) * N;
    #pragma unroll
    for (int q = 0; q < 4; q++){
      int c = (q * NTHR + tid) * 4;
      float4 a = ld4(Ar + c);
      Af[rr][2*q]   = __floats2half2_rn(a.x, a.y);
      Af[rr][2*q+1] = __floats2half2_rn(a.z, a.w);
    }
  }

  float4 ysbf[4], ysf[4];              // base / stage vector fragments (fp32)
  #pragma unroll
  for (int q = 0; q < 4; q++) ysbf[q] = ld4(x + (q * NTHR + tid) * 4);
  __syncthreads();

  const float t_end = (float)(*tptr);
  const float Tf    = (float)Tm;
  float t = 0.0f;
  float h = t_end * 0.01f;
  unsigned gen = 0;

  // matvec from registers: acc over our 16 cols, wave-reduce, park in part_sm
  auto mv = [&](){
    float acc[ROWS];
    #pragma unroll
    for (int rr = 0; rr < ROWS; rr++) acc[rr] = 0.0f;
    #pragma unroll
    for (int q = 0; q < 4; q++){
      float4 y = ysf[q];
      #pragma unroll
      for (int rr = 0; rr < ROWS; rr++){
        float2 lo = __half22float2(Af[rr][2*q]);
        float2 hi = __half22float2(Af[rr][2*q+1]);
        acc[rr] = fmaf(lo.x, y.x, fmaf(lo.y, y.y, fmaf(hi.x, y.z, fmaf(hi.y, y.w, acc[rr]))));
      }
    }
    __syncthreads();                   // part_sm free from previous stage
    #pragma unroll
    for (int rr = 0; rr < ROWS; rr++){
      float s = acc[rr];
      #pragma unroll
      for (int off = 32; off; off >>= 1) s += __shfl_xor(s, off, 64);
      if (lane == 0) part_sm[rr * 4 + wv] = s;
    }
    __syncthreads();
  };

  // k for row `tid` (tid<ROWS): y_s * (r + A@y_s + eps@P[d])
  auto kval = [&](float ts) -> float {
    int d = (int)((Tf * ts) / 30.0f);
    d = d < 0 ? 0 : (d > Tm ? Tm : d);
    float dot = part_sm[tid*4] + part_sm[tid*4+1] + part_sm[tid*4+2] + part_sm[tid*4+3];
    float ep = 0.f;
    #pragma unroll
    for (int p = 0; p < PERTS; p++) ep += eps_sh[tid * PERTS + p] * P_sh[d * PERTS + p];
    return ys_rows[tid] * (r_sh[tid] + dot + ep);
  };

  // ys = ysb + h * sum(cf[m] * khist[sli[m]]) over our 16 columns
  auto build = [&](const int* sli, const float* cf, int nk){
    #pragma unroll
    for (int q = 0; q < 4; q++){
      int c = (q * NTHR + tid) * 4;
      float4 v = ysbf[q];
      for (int m = 0; m < nk; m++){
        float cc = h * cf[m];
        float4 kv = ld4(&khist[sli[m]][c]);
        v.x = fmaf(cc, kv.x, v.x); v.y = fmaf(cc, kv.y, v.y);
        v.z = fmaf(cc, kv.z, v.z); v.w = fmaf(cc, kv.w, v.w);
      }
      ysf[q] = v;
      int o = c - rowbase;             // c,rowbase multiples of 4/16: full containment
      if (o >= 0 && o < ROWS) st4(&ys_rows[o], v);
    }
    __syncthreads();
  };

  // publish own 16 k's (+err), flag, flat detect, wide uncached pull
  auto exchange = [&](int slot, float kv, bool werr, float errv){
    ++gen;
    ull* kx = (gen & 1u) ? kx1u : kx0u;          // double buffer by parity
    if (wv == 0){
      float kvn = __shfl_down(kv, 1, 64);
      if ((lane & 1) == 0 && lane < ROWS){
        union { float2 f; ull u; } cv;
        cv.f = make_float2(kv, kvn);
        __hip_atomic_store(&kx[(rowbase >> 1) + (lane >> 1)], cv.u,
                           __ATOMIC_RELAXED, __HIP_MEMORY_SCOPE_AGENT);
      }
      if (werr && lane == 0)
        __hip_atomic_store(&err_part[b], errv, __ATOMIC_RELAXED, __HIP_MEMORY_SCOPE_AGENT);
    }
    __syncthreads();                             // all stage work done
    if (tid == 0){
      __builtin_amdgcn_sched_barrier(0);
      __builtin_amdgcn_s_waitcnt(0);             // kx/err stores at coherence point
      __builtin_amdgcn_sched_barrier(0);
      __hip_atomic_store(&flags[b], gen, __ATOMIC_RELAXED, __HIP_MEMORY_SCOPE_AGENT);
    }
    // ---- flat detect: every block's wave0 scans all 256 flags itself ----
    if (wv == 0){
      const ull* fl2 = reinterpret_cast<const ull*>(flags);  // 128 ull = 256 flags
      for (;;){
        ull v0 = __hip_atomic_load(&fl2[lane],      __ATOMIC_RELAXED, __HIP_MEMORY_SCOPE_AGENT);
        ull v1 = __hip_atomic_load(&fl2[64 + lane], __ATOMIC_RELAXED, __HIP_MEMORY_SCOPE_AGENT);
        bool ok = ((unsigned)v0 >= gen) && ((unsigned)(v0 >> 32) >= gen)
               && ((unsigned)v1 >= gen) && ((unsigned)(v1 >> 32) >= gen);
        if (__all(ok)) break;
        __builtin_amdgcn_s_sleep(2);
      }
      if (werr){
        // same order as R7's block-0 aggregator -> bitwise-identical es
        float es = 0.f;
        #pragma unroll
        for (int j = 0; j < 4; j++)
          es += __hip_atomic_load(&err_part[lane + j * 64],
                                  __ATOMIC_RELAXED, __HIP_MEMORY_SCOPE_AGENT);
        #pragma unroll
        for (int off = 32; off; off >>= 1) es += __shfl_xor(es, off, 64);
        if (lane == 0) es_sh = es;
      }
    }
    __syncthreads();                             // detect done, es_sh set
    // ---- wide uncached pull: 4x dwordx4 sc0 sc1 per thread = 16KB/block ----
    const float4* src = reinterpret_cast<const float4*>(kx);
    float4 a0, a1, a2, a3;
    asm volatile(
      "global_load_dwordx4 %0, %4, off sc0 sc1\n\t"
      "global_load_dwordx4 %1, %5, off sc0 sc1\n\t"
      "global_load_dwordx4 %2, %6, off sc0 sc1\n\t"
      "global_load_dwordx4 %3, %7, off sc0 sc1\n\t"
      "s_waitcnt vmcnt(0)"
      : "=&v"(a0), "=&v"(a1), "=&v"(a2), "=&v"(a3)
      : "v"(src + tid), "v"(src + 256 + tid), "v"(src + 512 + tid), "v"(src + 768 + tid)
      : "memory");
    float4* kh4 = reinterpret_cast<float4*>(&khist[slot][0]);
    kh4[tid]       = a0;
    kh4[256 + tid] = a1;
    kh4[512 + tid] = a2;
    kh4[768 + tid] = a3;
    __syncthreads();                             // khist[slot] ready
  };

  int sl[6] = {0, 1, 2, 3, 4, 5};      // logical k1..k6 -> physical LDS slots
  bool exhausted = true;

  for (int n = 0; n < MAXSTEP; ++n){
    if (n > 0){
      float es = es_sh;                          // set by last stage-7 exchange
      float enorm = sqrtf(es * (1.0f / (float)N));
      bool accept = (enorm <= 1.0f);
      if (accept){
        t += h;
        int tmp = sl[0]; sl[0] = sl[1]; sl[1] = tmp;  // FSAL: k1 <- k7 (in k2's slot)
        #pragma unroll
        for (int q = 0; q < 4; q++) ysbf[q] = ysf[q];
        if (tid < ROWS) ysb_rows[tid] = ys_rows[tid];
      }
      float fac = 0.9f * powf(enorm + 1e-10f, -0.2f);
      fac = fminf(fmaxf(fac, 0.2f), 10.0f);
      h *= fac;
      __syncthreads();
    }
    if (t >= t_end) { exhausted = false; break; }
    h = fminf(h, t_end - t);
    if (!(h > 0.0f)) { exhausted = false; break; }

    if (n == 0){
      // ---- stage 1 (once ever; FSAL covers later steps) ----
      #pragma unroll
      for (int q = 0; q < 4; q++){
        ysf[q] = ysbf[q];
        int c = (q * NTHR + tid) * 4, o = c - rowbase;
        if (o >= 0 && o < ROWS) st4(&ys_rows[o], ysf[q]);
      }
      __syncthreads();
      mv();
      float kv = (tid < ROWS) ? kval(t) : 0.f;
      exchange(sl[0], kv, false, 0.f);
    }

    // ---- stage 2 ----
    { const float cf[1] = {0.2f}; const int s_[1] = {sl[0]};
      build(s_, cf, 1); mv();
      float kv = (tid < ROWS) ? kval(t + 0.2f * h) : 0.f;
      exchange(sl[1], kv, false, 0.f); }

    // ---- stage 3 ----
    { const float cf[2] = {3.f/40.f, 9.f/40.f}; const int s_[2] = {sl[0], sl[1]};
      build(s_, cf, 2); mv();
      float kv = (tid < ROWS) ? kval(t + 0.3f * h) : 0.f;
      exchange(sl[2], kv, false, 0.f); }

    // ---- stage 4 ----
    { const float cf[3] = {44.f/45.f, -56.f/15.f, 32.f/9.f};
      const int s_[3] = {sl[0], sl[1], sl[2]};
      build(s_, cf, 3); mv();
      float kv = (tid < ROWS) ? kval(t + 0.8f * h) : 0.f;
      exchange(sl[3], kv, false, 0.f); }

    // ---- stage 5 ----
    { const float cf[4] = {19372.f/6561.f, -25360.f/2187.f, 64448.f/6561.f, -212.f/729.f};
      const int s_[4] = {sl[0], sl[1], sl[2], sl[3]};
      build(s_, cf, 4); mv();
      float kv = (tid < ROWS) ? kval(t + (8.f/9.f) * h) : 0.f;
      exchange(sl[4], kv, false, 0.f); }

    // ---- stage 6 ----
    { const float cf[5] = {9017.f/3168.f, -355.f/33.f, 46732.f/5247.f, 49.f/176.f, -5103.f/18656.f};
      const int s_[5] = {sl[0], sl[1], sl[2], sl[3], sl[4]};
      build(s_, cf, 5); mv();
      float kv = (tid < ROWS) ? kval(t + h) : 0.f;
      exchange(sl[5], kv, false, 0.f); }

    // ---- stage 7: ys = y5 candidate; err partial; k7 -> sl[1] (k2 dead) ----
    { const float cf[5] = {35.f/384.f, 500.f/1113.f, 125.f/192.f, -2187.f/6784.f, 11.f/84.f};
      const int s_[5] = {sl[0], sl[2], sl[3], sl[4], sl[5]};
      build(s_, cf, 5);                // ys == y5 candidate; ys_rows updated
      mv();
      float k7v = 0.f, errv = 0.f;
      if (tid < ROWS){
        k7v = kval(t + h);
        int gi = rowbase + tid;
        float e = (71.f/57600.f)  * khist[sl[0]][gi] - (71.f/16695.f)    * khist[sl[2]][gi]
                + (71.f/1920.f)   * khist[sl[3]][gi] - (17253.f/339200.f)* khist[sl[4]][gi]
                + (22.f/525.f)    * khist[sl[5]][gi] - (1.f/40.f)        * k7v;
        e *= h;
        float sc = 1e-6f + 1e-3f * fmaxf(fabsf(ysb_rows[tid]), fabsf(ys_rows[tid]));
        float q = e / sc;
        epr_sh[tid] = q * q;
      }
      __syncthreads();
      if (tid == 0){
        float s = 0.f;
        #pragma unroll
        for (int i = 0; i < ROWS; i++) s += epr_sh[i];
        errv = s;
      }
      exchange(sl[1], k7v, true, errv);          // barrier + err + k7 fetch
    }
  }

  if (exhausted){
    // apply the final (iteration 511) accept decision, as the reference does
    float es = es_sh;
    bool accept = sqrtf(es * (1.0f / (float)N)) <= 1.0f;
    if (tid < ROWS) out[rowbase + tid] = accept ? ys_rows[tid] : ysb_rows[tid];
  } else {
    if (tid < ROWS) out[rowbase + tid] = ysb_rows[tid];
  }
}

extern "C" void kernel_launch(void* const* d_in, const int* in_sizes, int n_in,
                              void* d_out, int out_size, void* d_ws, size_t ws_size,
                              hipStream_t stream)
{
  const float* x   = (const float*)d_in[0];
  const int*   tp  = (const int*)  d_in[1];
  const float* r   = (const float*)d_in[2];
  const float* A   = (const float*)d_in[3];
  const float* eps = (const float*)d_in[4];
  const float* Pm  = (const float*)d_in[5];
  float* out = (float*)d_out;
  float* W   = (float*)d_ws;
  int Tm = in_sizes[5] / PERTS - 1;   // P rows - 1  (== 30)

  // zero flags / err partials (ws re-poisoned per call)
  hipMemsetAsync(d_ws, 0, 4096, stream);
  mbpert_rk45_kernel<<<dim3(NBLK), dim3(NTHR), 0, stream>>>(
      x, tp, r, A, eps, Pm, out, W, Tm);
}